// Round 8
// baseline (69.252 us; speedup 1.0000x reference)
//
#include <hip/hip_runtime.h>
#include <hip/hip_bf16.h>
#include <float.h>
#include <math.h>

#define B  4
#define L  2048
#define D  512
#define K4 4

typedef __attribute__((ext_vector_type(8))) short  bf16x8;
typedef __attribute__((ext_vector_type(4))) float  f32x4;

// ---- ws layout (bytes) ----
// vmix tiled:  [b][kb=16][l=2048][32] bf16 = 8 MB
// Tt tiled:    [b][ls=64][n=512][32] bf16 = 8 MB
// wvT/woT tiled: [kb=16][n=512][32] bf16 = 512 KB each
#define VMIXB_OFF  0u
#define TT_OFF     8388608u
#define WVT_OFF    16777216u
#define WOT_OFF    17301504u
#define QPART_OFF  17825792u           // B*64*512 f32 = 512 KB
#define TPART_OFF  18350080u           // B*8*512 f32 = 64 KB
#define U_OFF      18415616u           // B*512 f32
#define SC_OFF     18423808u           // B*L f32

static __device__ __forceinline__ unsigned short f2b(float f) {
    __hip_bfloat16 h = __float2bfloat16(f);
    return *reinterpret_cast<unsigned short*>(&h);
}

// async global->LDS, 16B per lane; lds dest = wave-uniform base + lane*16
static __device__ __forceinline__ void gload16(const void* g, void* l) {
    __builtin_amdgcn_global_load_lds(
        (__attribute__((address_space(1))) void*)(g),
        (__attribute__((address_space(3))) void*)(l), 16, 0, 0);
}

// ---------------- 1) fused: qpart (blocks 0..127) || weight transpose->tiled bf16 (blocks 128..383) ----------------
__global__ __launch_bounds__(256) void k_prep1(const float* __restrict__ q,
                                               const float* __restrict__ wv, const float* __restrict__ wo,
                                               float* __restrict__ qpart,
                                               unsigned short* __restrict__ wvT, unsigned short* __restrict__ woT) {
    __shared__ float s[32][33];
    int bid = blockIdx.x, tid = threadIdx.x;
    if (bid < 128) {
        int b = bid >> 5, lc = bid & 31;
        int c4 = tid & 127, half = tid >> 7;
        const float4* p = (const float4*)q + ((size_t)b * L + lc * 64 + half * 32) * 128 + c4;
        float4 a = make_float4(0.f, 0.f, 0.f, 0.f);
#pragma unroll 8
        for (int l = 0; l < 32; ++l) {
            float4 x = p[(size_t)l * 128];
            a.x += x.x; a.y += x.y; a.z += x.z; a.w += x.w;
        }
        ((float4*)qpart)[((b * 64) + lc * 2 + half) * 128 + c4] = a;
    } else {
        int id2 = bid - 128;
        int c0 = (id2 >> 4) * 32, n0 = (id2 & 15) * 32;
        int kb = c0 >> 5;
        int col = tid & 31, r8 = tid >> 5;
        for (int z = 0; z < 2; ++z) {
            const float* src = z ? wo : wv;
            unsigned short* dst = z ? woT : wvT;
#pragma unroll
            for (int rr = 0; rr < 4; ++rr) {
                int r = rr * 8 + r8;
                s[r][col] = src[(size_t)(c0 + r) * D + n0 + col];
            }
            __syncthreads();
#pragma unroll
            for (int rr = 0; rr < 4; ++rr) {
                int r = rr * 8 + r8;
                // element (n = n0+r, c = c0+col) -> tiled [kb][n][c%32]
                dst[((size_t)kb * 512 + n0 + r) * 32 + col] = f2b(s[col][r]);
            }
            __syncthreads();
        }
    }
}

// ---------------- 2a) tpart[b][jc][m] = sum_{j in chunk jc} wq[j][m] * qsum[b][j] ----------------
__global__ void k_tpart(const float* __restrict__ wq, const float* __restrict__ qpart,
                        float* __restrict__ tpart) {
    __shared__ float part[256];
    __shared__ float qs[64];
    int b = blockIdx.x, jc = blockIdx.y, tid = threadIdx.x;
    int jj = tid & 63, cg = tid >> 6;
    float p = 0.f;
#pragma unroll
    for (int c = cg * 16; c < cg * 16 + 16; ++c)
        p += qpart[((b * 64) + c) * D + jc * 64 + jj];
    part[tid] = p;
    __syncthreads();
    if (tid < 64) qs[tid] = part[tid] + part[tid + 64] + part[tid + 128] + part[tid + 192];
    __syncthreads();
    float a0 = 0.f, a1 = 0.f;
#pragma unroll 8
    for (int j = 0; j < 64; ++j) {
        const float* wr = wq + (size_t)(jc * 64 + j) * D;
        float qv = qs[j];
        a0 += wr[tid] * qv;
        a1 += wr[tid + 256] * qv;
    }
    tpart[((b * 8) + jc) * D + tid] = a0;
    tpart[((b * 8) + jc) * D + tid + 256] = a1;
}

// ---------------- 2b) u[b][i] = (1/16384) sum_m wk[i][m] * t[b][m] ----------------
__global__ void k_uvec(const float* __restrict__ wk, const float* __restrict__ tpart,
                       float* __restrict__ u) {
    __shared__ __align__(16) float ts[D];
    int b = blockIdx.x, tid = threadIdx.x;
    for (int d = tid; d < D; d += 256) {
        float s = 0.f;
#pragma unroll
        for (int c = 0; c < 8; ++c) s += tpart[((b * 8) + c) * D + d];
        ts[d] = s;
    }
    __syncthreads();
    int wave = tid >> 6, lane = tid & 63;
    const float4* wk4 = (const float4*)wk;
    float4 t0 = *(const float4*)&ts[lane * 4];
    float4 t1 = *(const float4*)&ts[256 + lane * 4];
#pragma unroll
    for (int rr = 0; rr < 4; ++rr) {
        int i = blockIdx.y * 16 + wave * 4 + rr;
        float4 w0 = wk4[(size_t)i * 128 + lane];
        float4 w1 = wk4[(size_t)i * 128 + 64 + lane];
        float acc = w0.x * t0.x + w0.y * t0.y + w0.z * t0.z + w0.w * t0.w
                  + w1.x * t1.x + w1.y * t1.y + w1.z * t1.z + w1.w * t1.w;
        for (int m = 32; m; m >>= 1) acc += __shfl_xor(acc, m, 64);
        if (lane == 0) u[b * D + i] = acc * (1.f / 16384.f);
    }
}

// ---------------- 3) scores[b][j] = keys[b,j,:] . u[b,:] ----------------
__global__ void k_scores(const float* __restrict__ keys, const float* __restrict__ u,
                         float* __restrict__ sc) {
    __shared__ __align__(16) float us[D];
    int b = blockIdx.x, tid = threadIdx.x;
    for (int d = tid; d < D; d += 256) us[d] = u[b * D + d];
    __syncthreads();
    int wave = tid >> 6, lane = tid & 63;
    int j = blockIdx.y * 4 + wave;
    const float4* kp = (const float4*)(keys + ((size_t)b * L + j) * D);
    float4 u0 = *(const float4*)&us[lane * 4];
    float4 u1 = *(const float4*)&us[256 + lane * 4];
    float4 x0 = kp[lane], x1 = kp[lane + 64];
    float acc = x0.x * u0.x + x0.y * u0.y + x0.z * u0.z + x0.w * u0.w
              + x1.x * u1.x + x1.y * u1.y + x1.z * u1.z + x1.w * u1.w;
    for (int m = 32; m; m >>= 1) acc += __shfl_xor(acc, m, 64);
    if (lane == 0) sc[b * L + j] = acc;
}

// ---------------- 4) vmixb (tiled out) with inlined top-4+softmax prologue ----------------
// grid 2048: b = bid>>9, kb = (bid>>5)&15, lgrp = bid&31 (64 l-rows each)
__global__ __launch_bounds__(256) void k_vmixb(const float* __restrict__ values,
                                               const float* __restrict__ sc,
                                               unsigned short* __restrict__ vmixb) {
    __shared__ float sv[L];
    __shared__ float wv4[4]; __shared__ int wi4[4];
    __shared__ float wsh[K4]; __shared__ int ish[K4];
    int tid = threadIdx.x;
    int wave = tid >> 6, lane = tid & 63;
    int bid = blockIdx.x;
    int b = bid >> 9;
    for (int i = tid; i < L; i += 256) sv[i] = sc[b * L + i];
    __syncthreads();
    float topv[K4]; int topi[K4];
    for (int it = 0; it < K4; ++it) {
        float bv = -FLT_MAX;
        int bi = 0x7fffffff;
#pragma unroll
        for (int i = 0; i < 8; ++i) {
            int idx = tid + i * 256;
            float v = sv[idx];
            if (v > bv) { bv = v; bi = idx; }    // ascending scan: strict > keeps lowest idx
        }
        for (int m = 32; m; m >>= 1) {
            float v2 = __shfl_xor(bv, m, 64);
            int i2 = __shfl_xor(bi, m, 64);
            if (v2 > bv || (v2 == bv && i2 < bi)) { bv = v2; bi = i2; }
        }
        if (lane == 0) { wv4[wave] = bv; wi4[wave] = bi; }
        __syncthreads();
        float mv = wv4[0]; int mi = wi4[0];
#pragma unroll
        for (int w = 1; w < 4; ++w)
            if (wv4[w] > mv || (wv4[w] == mv && wi4[w] < mi)) { mv = wv4[w]; mi = wi4[w]; }
        topv[it] = mv; topi[it] = mi;
        if (tid == 0) sv[mi] = -FLT_MAX;
        __syncthreads();
    }
    if (tid == 0) {
        float mx = topv[0];
#pragma unroll
        for (int i = 1; i < K4; ++i) mx = fmaxf(mx, topv[i]);
        float ssum = 0.f, e[K4];
#pragma unroll
        for (int i = 0; i < K4; ++i) { e[i] = expf(topv[i] - mx); ssum += e[i]; }
#pragma unroll
        for (int i = 0; i < K4; ++i) { wsh[i] = e[i] / ssum; ish[i] = topi[i]; }
    }
    __syncthreads();

    int kb = (bid >> 5) & 15;
    int l  = (bid & 31) * 64 + (tid >> 2);
    int ko = (tid & 3) * 8;
    const float4* vp = (const float4*)values;
    float4 r0 = make_float4(0.f, 0.f, 0.f, 0.f), r1 = r0;
#pragma unroll
    for (int j = 0; j < K4; ++j) {
        int ls = (l + ish[j]) & (L - 1);
        const float4* p = vp + ((size_t)b * L + ls) * 128 + kb * 8 + (tid & 3) * 2;
        float4 x0 = p[0], x1 = p[1];
        float w = wsh[j];
        r0.x += w * x0.x; r0.y += w * x0.y; r0.z += w * x0.z; r0.w += w * x0.w;
        r1.x += w * x1.x; r1.y += w * x1.y; r1.z += w * x1.z; r1.w += w * x1.w;
    }
    uint4 o;
    o.x = (unsigned)f2b(r0.x) | ((unsigned)f2b(r0.y) << 16);
    o.y = (unsigned)f2b(r0.z) | ((unsigned)f2b(r0.w) << 16);
    o.z = (unsigned)f2b(r1.x) | ((unsigned)f2b(r1.y) << 16);
    o.w = (unsigned)f2b(r1.z) | ((unsigned)f2b(r1.w) << 16);
    size_t off = ((size_t)(b * 16 + kb) * 2048 + l) * 32 + ko;   // ushort units, 16B aligned
    *(uint4*)(vmixb + off) = o;
}

// ---------------- 5) GEMM1: tiled vmix @ tiled wvT -> tiled Tt; gload_lds staging, dbuf 1-barrier ----------------
__global__ __launch_bounds__(256) void k_gemm1(const unsigned short* __restrict__ A,
                                               const unsigned short* __restrict__ Bt,
                                               unsigned short* __restrict__ Tt) {
    __shared__ __align__(16) unsigned short As[2][128][32];
    __shared__ __align__(16) unsigned short Bs[2][64][32];
    int m0 = blockIdx.x * 128, n0 = blockIdx.y * 64;
    int b = m0 >> 11, ml = m0 & (L - 1);
    int tid = threadIdx.x;
    int wave = tid >> 6, lane = tid & 63;
    int wr = wave >> 1, wc = wave & 1;
    int lr = lane & 15, lg = lane >> 4;
    f32x4 acc[4][2];
#pragma unroll
    for (int i = 0; i < 4; ++i)
#pragma unroll
        for (int j = 0; j < 2; ++j) acc[i][j] = (f32x4){0.f, 0.f, 0.f, 0.f};

    int lbyte = tid * 16;            // per-lane linear byte in tile
    int wbase = (tid >> 6) * 1024;   // wave-uniform LDS byte base

#define STAGE1(buf, kb)                                                                   \
    {                                                                                     \
        const char* gA = (const char*)(A + ((size_t)(b * 16 + (kb)) * 2048 + ml) * 32);   \
        const char* gB = (const char*)(Bt + ((size_t)(kb) * 512 + n0) * 32);              \
        char* lA = ((char*)&As[buf][0][0]) + wbase;                                       \
        char* lB = ((char*)&Bs[buf][0][0]) + wbase;                                       \
        gload16(gA + lbyte, lA);                                                          \
        gload16(gA + 4096 + lbyte, lA + 4096);                                            \
        gload16(gB + lbyte, lB);                                                          \
    }

    STAGE1(0, 0);
    __syncthreads();
    int cur = 0;
    for (int t = 0; t < 15; ++t) {
        STAGE1(cur ^ 1, t + 1);
        bf16x8 a[4], bq[2];
#pragma unroll
        for (int i = 0; i < 4; ++i) a[i] = *(const bf16x8*)&As[cur][wr * 64 + i * 16 + lr][lg * 8];
#pragma unroll
        for (int j = 0; j < 2; ++j) bq[j] = *(const bf16x8*)&Bs[cur][wc * 32 + j * 16 + lr][lg * 8];
#pragma unroll
        for (int i = 0; i < 4; ++i)
#pragma unroll
            for (int j = 0; j < 2; ++j)
                acc[i][j] = __builtin_amdgcn_mfma_f32_16x16x32_bf16(a[i], bq[j], acc[i][j], 0, 0, 0);
        __syncthreads();
        cur ^= 1;
    }
    {
        bf16x8 a[4], bq[2];
#pragma unroll
        for (int i = 0; i < 4; ++i) a[i] = *(const bf16x8*)&As[cur][wr * 64 + i * 16 + lr][lg * 8];
#pragma unroll
        for (int j = 0; j < 2; ++j) bq[j] = *(const bf16x8*)&Bs[cur][wc * 32 + j * 16 + lr][lg * 8];
#pragma unroll
        for (int i = 0; i < 4; ++i)
#pragma unroll
            for (int j = 0; j < 2; ++j)
                acc[i][j] = __builtin_amdgcn_mfma_f32_16x16x32_bf16(a[i], bq[j], acc[i][j], 0, 0, 0);
    }
#undef STAGE1
#pragma unroll
    for (int i = 0; i < 4; ++i) {
        int lglob = ml + wr * 64 + i * 16 + lg * 4;
        int ls = lglob >> 5, lo = lglob & 31;
#pragma unroll
        for (int j = 0; j < 2; ++j) {
            int cn = n0 + wc * 32 + j * 16 + lr;
            uint2 pk;
            pk.x = (unsigned)f2b(acc[i][j][0]) | ((unsigned)f2b(acc[i][j][1]) << 16);
            pk.y = (unsigned)f2b(acc[i][j][2]) | ((unsigned)f2b(acc[i][j][3]) << 16);
            *(uint2*)&Tt[((size_t)(b * 64 + ls) * 512 + cn) * 32 + lo] = pk;
        }
    }
}

// ---------------- 6) GEMM2: tiled Tt @ tiled woT -> out (permuted fp32 store); gload_lds staging ----------------
__global__ __launch_bounds__(256) void k_gemm2(const unsigned short* __restrict__ Tt,
                                               const unsigned short* __restrict__ Bt,
                                               float* __restrict__ out) {
    __shared__ __align__(16) unsigned short As[2][128][32];
    __shared__ __align__(16) unsigned short Bs[2][64][32];
    int m0 = blockIdx.x * 128, n0 = blockIdx.y * 64;
    int bs = blockIdx.z;
    int bb = bs >> 2, s = bs & 3;
    int tid = threadIdx.x;
    int wave = tid >> 6, lane = tid & 63;
    int wr = wave >> 1, wc = wave & 1;
    int lr = lane & 15, lg = lane >> 4;
    f32x4 acc[4][2];
#pragma unroll
    for (int i = 0; i < 4; ++i)
#pragma unroll
        for (int j = 0; j < 2; ++j) acc[i][j] = (f32x4){0.f, 0.f, 0.f, 0.f};

    int lbyte = tid * 16;
    int wbase = (tid >> 6) * 1024;

#define STAGE2(buf, t)                                                                        \
    {                                                                                         \
        const char* gA = (const char*)(Tt + ((size_t)(bb * 64 + s * 16 + (t)) * 512 + m0) * 32); \
        const char* gB = (const char*)(Bt + ((size_t)(t) * 512 + n0) * 32);                   \
        char* lA = ((char*)&As[buf][0][0]) + wbase;                                           \
        char* lB = ((char*)&Bs[buf][0][0]) + wbase;                                           \
        gload16(gA + lbyte, lA);                                                              \
        gload16(gA + 4096 + lbyte, lA + 4096);                                                \
        gload16(gB + lbyte, lB);                                                              \
    }

    STAGE2(0, 0);
    __syncthreads();
    int cur = 0;
    for (int t = 0; t < 15; ++t) {
        STAGE2(cur ^ 1, t + 1);
        bf16x8 a[4], bq[2];
#pragma unroll
        for (int i = 0; i < 4; ++i) a[i] = *(const bf16x8*)&As[cur][wr * 64 + i * 16 + lr][lg * 8];
#pragma unroll
        for (int j = 0; j < 2; ++j) bq[j] = *(const bf16x8*)&Bs[cur][wc * 32 + j * 16 + lr][lg * 8];
#pragma unroll
        for (int i = 0; i < 4; ++i)
#pragma unroll
            for (int j = 0; j < 2; ++j)
                acc[i][j] = __builtin_amdgcn_mfma_f32_16x16x32_bf16(a[i], bq[j], acc[i][j], 0, 0, 0);
        __syncthreads();
        cur ^= 1;
    }
    {
        bf16x8 a[4], bq[2];
#pragma unroll
        for (int i = 0; i < 4; ++i) a[i] = *(const bf16x8*)&As[cur][wr * 64 + i * 16 + lr][lg * 8];
#pragma unroll
        for (int j = 0; j < 2; ++j) bq[j] = *(const bf16x8*)&Bs[cur][wc * 32 + j * 16 + lr][lg * 8];
#pragma unroll
        for (int i = 0; i < 4; ++i)
#pragma unroll
            for (int j = 0; j < 2; ++j)
                acc[i][j] = __builtin_amdgcn_mfma_f32_16x16x32_bf16(a[i], bq[j], acc[i][j], 0, 0, 0);
    }
#undef STAGE2
#pragma unroll
    for (int i = 0; i < 4; ++i) {
#pragma unroll
        for (int j = 0; j < 2; ++j) {
            int n = n0 + wc * 32 + j * 16 + lr;
#pragma unroll
            for (int r = 0; r < 4; ++r) {
                int m = m0 + wr * 64 + i * 16 + lg * 4 + r;
                int rr = ((m & 63) << 5) | ((m >> 6) << 2) | s;
                out[((size_t)bb * L + rr) * D + n] = acc[i][j][r];
            }
        }
    }
}

extern "C" void kernel_launch(void* const* d_in, const int* in_sizes, int n_in,
                              void* d_out, int out_size, void* d_ws, size_t ws_size,
                              hipStream_t stream) {
    const float* queries = (const float*)d_in[0];
    const float* keys    = (const float*)d_in[1];
    const float* values  = (const float*)d_in[2];
    const float* wq      = (const float*)d_in[3];
    const float* wk      = (const float*)d_in[4];
    const float* wv      = (const float*)d_in[5];
    const float* wo      = (const float*)d_in[6];
    float* out = (float*)d_out;
    char* ws = (char*)d_ws;

    unsigned short* vmixb = (unsigned short*)(ws + VMIXB_OFF);
    unsigned short* Tt    = (unsigned short*)(ws + TT_OFF);
    unsigned short* wvT   = (unsigned short*)(ws + WVT_OFF);
    unsigned short* woT   = (unsigned short*)(ws + WOT_OFF);
    float* qpart = (float*)(ws + QPART_OFF);
    float* tpart = (float*)(ws + TPART_OFF);
    float* u     = (float*)(ws + U_OFF);
    float* sc    = (float*)(ws + SC_OFF);

    k_prep1<<<384, 256, 0, stream>>>(queries, wv, wo, qpart, wvT, woT);
    k_tpart<<<dim3(B, 8), 256, 0, stream>>>(wq, qpart, tpart);
    k_uvec<<<dim3(B, 32), 256, 0, stream>>>(wk, tpart, u);
    k_scores<<<dim3(B, 512), 256, 0, stream>>>(keys, u, sc);
    k_vmixb<<<2048, 256, 0, stream>>>(values, sc, vmixb);
    k_gemm1<<<dim3(64, 8), 256, 0, stream>>>(vmixb, wvT, Tt);
    k_gemm2<<<dim3(4, 8, 16), 256, 0, stream>>>(Tt, woT, out);
}

// Round 9
// 66.411 us; speedup vs baseline: 1.0428x; 1.0428x over previous
//
#include <hip/hip_runtime.h>
#include <hip/hip_bf16.h>
#include <float.h>
#include <math.h>

#define B  4
#define L  2048
#define D  512
#define K4 4

typedef __attribute__((ext_vector_type(8))) short  bf16x8;
typedef __attribute__((ext_vector_type(4))) float  f32x4;

// ---- ws layout (bytes) ----
#define VMIXB_OFF  0u                  // B*L*D bf16 = 8 MB
#define TT_OFF     8388608u            // B*512*2048 bf16 = 8 MB
#define WVT_OFF    16777216u           // 512*512 bf16
#define WOT_OFF    17301504u
#define QPART_OFF  17825792u           // B*64*512 f32 = 512 KB
#define TPART_OFF  18350080u           // B*8*512 f32 = 64 KB
#define U_OFF      18415616u           // B*512 f32
#define SC_OFF     18423808u           // B*L f32

static __device__ __forceinline__ unsigned short f2b(float f) {
    __hip_bfloat16 h = __float2bfloat16(f);
    return *reinterpret_cast<unsigned short*>(&h);
}

// ---------------- 1) fused: qpart (blocks 0..127) || weight transpose (blocks 128..383) ----------------
__global__ __launch_bounds__(256) void k_prep1(const float* __restrict__ q,
                                               const float* __restrict__ wv, const float* __restrict__ wo,
                                               float* __restrict__ qpart,
                                               unsigned short* __restrict__ wvT, unsigned short* __restrict__ woT) {
    __shared__ float s[32][33];
    int bid = blockIdx.x, tid = threadIdx.x;
    if (bid < 128) {
        int b = bid >> 5, lc = bid & 31;
        int c4 = tid & 127, half = tid >> 7;
        const float4* p = (const float4*)q + ((size_t)b * L + lc * 64 + half * 32) * 128 + c4;
        float4 a = make_float4(0.f, 0.f, 0.f, 0.f);
#pragma unroll 8
        for (int l = 0; l < 32; ++l) {
            float4 x = p[(size_t)l * 128];
            a.x += x.x; a.y += x.y; a.z += x.z; a.w += x.w;
        }
        ((float4*)qpart)[((b * 64) + lc * 2 + half) * 128 + c4] = a;
    } else {
        int id2 = bid - 128;
        int c0 = (id2 >> 4) * 32, n0 = (id2 & 15) * 32;
        int col = tid & 31, r8 = tid >> 5;
        for (int z = 0; z < 2; ++z) {
            const float* src = z ? wo : wv;
            unsigned short* dst = z ? woT : wvT;
#pragma unroll
            for (int rr = 0; rr < 4; ++rr) {
                int r = rr * 8 + r8;
                s[r][col] = src[(size_t)(c0 + r) * D + n0 + col];
            }
            __syncthreads();
#pragma unroll
            for (int rr = 0; rr < 4; ++rr) {
                int r = rr * 8 + r8;
                dst[(size_t)(n0 + r) * D + c0 + col] = f2b(s[col][r]);
            }
            __syncthreads();
        }
    }
}

// ---------------- 2a) tpart[b][jc][m] = sum_{j in chunk jc} wq[j][m] * qsum[b][j] ----------------
__global__ void k_tpart(const float* __restrict__ wq, const float* __restrict__ qpart,
                        float* __restrict__ tpart) {
    __shared__ float part[256];
    __shared__ float qs[64];
    int b = blockIdx.x, jc = blockIdx.y, tid = threadIdx.x;
    int jj = tid & 63, cg = tid >> 6;
    float p = 0.f;
#pragma unroll
    for (int c = cg * 16; c < cg * 16 + 16; ++c)
        p += qpart[((b * 64) + c) * D + jc * 64 + jj];
    part[tid] = p;
    __syncthreads();
    if (tid < 64) qs[tid] = part[tid] + part[tid + 64] + part[tid + 128] + part[tid + 192];
    __syncthreads();
    float a0 = 0.f, a1 = 0.f;
#pragma unroll 8
    for (int j = 0; j < 64; ++j) {
        const float* wr = wq + (size_t)(jc * 64 + j) * D;
        float qv = qs[j];
        a0 += wr[tid] * qv;
        a1 += wr[tid + 256] * qv;
    }
    tpart[((b * 8) + jc) * D + tid] = a0;
    tpart[((b * 8) + jc) * D + tid + 256] = a1;
}

// ---------------- 2b) u[b][i] = (1/16384) sum_m wk[i][m] * t[b][m] ----------------
__global__ void k_uvec(const float* __restrict__ wk, const float* __restrict__ tpart,
                       float* __restrict__ u) {
    __shared__ __align__(16) float ts[D];
    int b = blockIdx.x, tid = threadIdx.x;
    for (int d = tid; d < D; d += 256) {
        float s = 0.f;
#pragma unroll
        for (int c = 0; c < 8; ++c) s += tpart[((b * 8) + c) * D + d];
        ts[d] = s;
    }
    __syncthreads();
    int wave = tid >> 6, lane = tid & 63;
    const float4* wk4 = (const float4*)wk;
    float4 t0 = *(const float4*)&ts[lane * 4];
    float4 t1 = *(const float4*)&ts[256 + lane * 4];
#pragma unroll
    for (int rr = 0; rr < 4; ++rr) {
        int i = blockIdx.y * 16 + wave * 4 + rr;
        float4 w0 = wk4[(size_t)i * 128 + lane];
        float4 w1 = wk4[(size_t)i * 128 + 64 + lane];
        float acc = w0.x * t0.x + w0.y * t0.y + w0.z * t0.z + w0.w * t0.w
                  + w1.x * t1.x + w1.y * t1.y + w1.z * t1.z + w1.w * t1.w;
        for (int m = 32; m; m >>= 1) acc += __shfl_xor(acc, m, 64);
        if (lane == 0) u[b * D + i] = acc * (1.f / 16384.f);
    }
}

// ---------------- 3) scores: 16 rows/block, grid (B,128) ----------------
__global__ void k_scores(const float* __restrict__ keys, const float* __restrict__ u,
                         float* __restrict__ sc) {
    __shared__ __align__(16) float us[D];
    int b = blockIdx.x, tid = threadIdx.x;
    for (int d = tid; d < D; d += 256) us[d] = u[b * D + d];
    __syncthreads();
    int wave = tid >> 6, lane = tid & 63;
    float4 u0 = *(const float4*)&us[lane * 4];
    float4 u1 = *(const float4*)&us[256 + lane * 4];
#pragma unroll
    for (int rr = 0; rr < 4; ++rr) {
        int j = blockIdx.y * 16 + wave * 4 + rr;
        const float4* kp = (const float4*)(keys + ((size_t)b * L + j) * D);
        float4 x0 = kp[lane], x1 = kp[lane + 64];
        float acc = x0.x * u0.x + x0.y * u0.y + x0.z * u0.z + x0.w * u0.w
                  + x1.x * u1.x + x1.y * u1.y + x1.z * u1.z + x1.w * u1.w;
        for (int m = 32; m; m >>= 1) acc += __shfl_xor(acc, m, 64);
        if (lane == 0) sc[b * L + j] = acc;
    }
}

// ---------------- 4) vmixb: 512 blocks x 4 l-tiles, inlined top-4+softmax prologue ----------------
__global__ __launch_bounds__(256) void k_vmixb(const float* __restrict__ values,
                                               const float* __restrict__ sc,
                                               uint4* __restrict__ vmixb) {
    __shared__ float sv[L];
    __shared__ float wv4[4]; __shared__ int wi4[4];
    __shared__ float wsh[K4]; __shared__ int ish[K4];
    int tid = threadIdx.x;
    int wave = tid >> 6, lane = tid & 63;
    int bid = blockIdx.x;
    int b = bid >> 7;                  // 128 blocks per batch
    for (int i = tid; i < L; i += 256) sv[i] = sc[b * L + i];
    __syncthreads();
    float topv[K4]; int topi[K4];
    for (int it = 0; it < K4; ++it) {
        float bv = -FLT_MAX;
        int bi = 0x7fffffff;
#pragma unroll
        for (int i = 0; i < 8; ++i) {
            int idx = tid + i * 256;
            float v = sv[idx];
            if (v > bv) { bv = v; bi = idx; }    // ascending scan: strict > keeps lowest idx
        }
        for (int m = 32; m; m >>= 1) {
            float v2 = __shfl_xor(bv, m, 64);
            int i2 = __shfl_xor(bi, m, 64);
            if (v2 > bv || (v2 == bv && i2 < bi)) { bv = v2; bi = i2; }
        }
        if (lane == 0) { wv4[wave] = bv; wi4[wave] = bi; }
        __syncthreads();
        float mv = wv4[0]; int mi = wi4[0];
#pragma unroll
        for (int w = 1; w < 4; ++w)
            if (wv4[w] > mv || (wv4[w] == mv && wi4[w] < mi)) { mv = wv4[w]; mi = wi4[w]; }
        topv[it] = mv; topi[it] = mi;
        if (tid == 0) sv[mi] = -FLT_MAX;
        __syncthreads();
    }
    if (tid == 0) {
        float mx = topv[0];
#pragma unroll
        for (int i = 1; i < K4; ++i) mx = fmaxf(mx, topv[i]);
        float ssum = 0.f, e[K4];
#pragma unroll
        for (int i = 0; i < K4; ++i) { e[i] = expf(topv[i] - mx); ssum += e[i]; }
#pragma unroll
        for (int i = 0; i < K4; ++i) { wsh[i] = e[i] / ssum; ish[i] = topi[i]; }
    }
    __syncthreads();

    const float4* vp = (const float4*)values;
#pragma unroll
    for (int it = 0; it < 4; ++it) {
        size_t t = ((size_t)bid * 4 + it) * 256 + tid;
        int l  = (int)((t >> 6) & (L - 1));
        int g8 = (int)(t & 63);
        float4 r0 = make_float4(0.f, 0.f, 0.f, 0.f), r1 = r0;
#pragma unroll
        for (int j = 0; j < K4; ++j) {
            int ls = (l + ish[j]) & (L - 1);
            const float4* p = vp + ((size_t)b * L + ls) * 128 + g8 * 2;
            float4 x0 = p[0], x1 = p[1];
            float w = wsh[j];
            r0.x += w * x0.x; r0.y += w * x0.y; r0.z += w * x0.z; r0.w += w * x0.w;
            r1.x += w * x1.x; r1.y += w * x1.y; r1.z += w * x1.z; r1.w += w * x1.w;
        }
        uint4 o;
        o.x = (unsigned)f2b(r0.x) | ((unsigned)f2b(r0.y) << 16);
        o.y = (unsigned)f2b(r0.z) | ((unsigned)f2b(r0.w) << 16);
        o.z = (unsigned)f2b(r1.x) | ((unsigned)f2b(r1.y) << 16);
        o.w = (unsigned)f2b(r1.z) | ((unsigned)f2b(r1.w) << 16);
        vmixb[t] = o;
    }
}

// ---------------- 5) GEMM1: Tt[b][n][l] = bf16( vmixb @ wvT^T ), 128x64 tile, dbuf 1-barrier ----------------
__global__ __launch_bounds__(256) void k_gemm1(const unsigned short* __restrict__ A,
                                               const unsigned short* __restrict__ Bt,
                                               unsigned short* __restrict__ Tt) {
    __shared__ __align__(16) unsigned short As[2][128][40];
    __shared__ __align__(16) unsigned short Bs[2][64][40];
    int m0 = blockIdx.x * 128, n0 = blockIdx.y * 64;
    int tid = threadIdx.x;
    int wave = tid >> 6, lane = tid & 63;
    int wr = wave >> 1, wc = wave & 1;
    int lr = lane & 15, lg = lane >> 4;
    f32x4 acc[4][2];
#pragma unroll
    for (int i = 0; i < 4; ++i)
#pragma unroll
        for (int j = 0; j < 2; ++j) acc[i][j] = (f32x4){0.f, 0.f, 0.f, 0.f};

    int aR = tid >> 1, aC = (tid & 1) * 16;
    int bR = tid >> 2, bC = (tid & 3) * 8;
    const unsigned short* Ap = A + (size_t)(m0 + aR) * D + aC;
    const unsigned short* Bp = Bt + (size_t)(n0 + bR) * D + bC;
    {
        uint4 va0 = *(const uint4*)(Ap);
        uint4 va1 = *(const uint4*)(Ap + 8);
        uint4 vb  = *(const uint4*)(Bp);
        *(uint4*)&As[0][aR][aC]     = va0;
        *(uint4*)&As[0][aR][aC + 8] = va1;
        *(uint4*)&Bs[0][bR][bC]     = vb;
    }
    __syncthreads();
    int cur = 0;
    for (int t = 0; t < 15; ++t) {
        int k0 = (t + 1) * 32;
        uint4 va0 = *(const uint4*)(Ap + k0);
        uint4 va1 = *(const uint4*)(Ap + k0 + 8);
        uint4 vb  = *(const uint4*)(Bp + k0);
        bf16x8 a[4], bq[2];
#pragma unroll
        for (int i = 0; i < 4; ++i) a[i] = *(const bf16x8*)&As[cur][wr * 64 + i * 16 + lr][lg * 8];
#pragma unroll
        for (int j = 0; j < 2; ++j) bq[j] = *(const bf16x8*)&Bs[cur][wc * 32 + j * 16 + lr][lg * 8];
#pragma unroll
        for (int i = 0; i < 4; ++i)
#pragma unroll
            for (int j = 0; j < 2; ++j)
                acc[i][j] = __builtin_amdgcn_mfma_f32_16x16x32_bf16(a[i], bq[j], acc[i][j], 0, 0, 0);
        *(uint4*)&As[cur ^ 1][aR][aC]     = va0;
        *(uint4*)&As[cur ^ 1][aR][aC + 8] = va1;
        *(uint4*)&Bs[cur ^ 1][bR][bC]     = vb;
        __syncthreads();
        cur ^= 1;
    }
    {
        bf16x8 a[4], bq[2];
#pragma unroll
        for (int i = 0; i < 4; ++i) a[i] = *(const bf16x8*)&As[cur][wr * 64 + i * 16 + lr][lg * 8];
#pragma unroll
        for (int j = 0; j < 2; ++j) bq[j] = *(const bf16x8*)&Bs[cur][wc * 32 + j * 16 + lr][lg * 8];
#pragma unroll
        for (int i = 0; i < 4; ++i)
#pragma unroll
            for (int j = 0; j < 2; ++j)
                acc[i][j] = __builtin_amdgcn_mfma_f32_16x16x32_bf16(a[i], bq[j], acc[i][j], 0, 0, 0);
    }
    int bb = m0 >> 11;
    int lbase = (m0 & (L - 1)) + wr * 64 + lg * 4;
#pragma unroll
    for (int i = 0; i < 4; ++i) {
        int lp = lbase + i * 16;
#pragma unroll
        for (int j = 0; j < 2; ++j) {
            int cn = n0 + wc * 32 + j * 16 + lr;
            uint2 pk;
            pk.x = (unsigned)f2b(acc[i][j][0]) | ((unsigned)f2b(acc[i][j][1]) << 16);
            pk.y = (unsigned)f2b(acc[i][j][2]) | ((unsigned)f2b(acc[i][j][3]) << 16);
            *(uint2*)&Tt[((size_t)bb * D + cn) * L + lp] = pk;
        }
    }
}

// ---------------- 6) GEMM2: out[b][perm(m,s)][n] = Tt_slice @ woT^T, permuted fp32 store ----------------
__global__ __launch_bounds__(256) void k_gemm2(const unsigned short* __restrict__ Tt,
                                               const unsigned short* __restrict__ Bt,
                                               float* __restrict__ out) {
    __shared__ __align__(16) unsigned short As[2][128][40];
    __shared__ __align__(16) unsigned short Bs[2][64][40];
    int m0 = blockIdx.x * 128, n0 = blockIdx.y * 64;
    int bs = blockIdx.z;
    int bb = bs >> 2, s = bs & 3;
    const unsigned short* Ab = Tt + (size_t)bb * D * L + (size_t)s * 512;
    int tid = threadIdx.x;
    int wave = tid >> 6, lane = tid & 63;
    int wr = wave >> 1, wc = wave & 1;
    int lr = lane & 15, lg = lane >> 4;
    f32x4 acc[4][2];
#pragma unroll
    for (int i = 0; i < 4; ++i)
#pragma unroll
        for (int j = 0; j < 2; ++j) acc[i][j] = (f32x4){0.f, 0.f, 0.f, 0.f};

    int aR = tid >> 1, aC = (tid & 1) * 16;
    int bR = tid >> 2, bC = (tid & 3) * 8;
    const unsigned short* Ap = Ab + (size_t)(m0 + aR) * L + aC;
    const unsigned short* Bp = Bt + (size_t)(n0 + bR) * D + bC;
    {
        uint4 va0 = *(const uint4*)(Ap);
        uint4 va1 = *(const uint4*)(Ap + 8);
        uint4 vb  = *(const uint4*)(Bp);
        *(uint4*)&As[0][aR][aC]     = va0;
        *(uint4*)&As[0][aR][aC + 8] = va1;
        *(uint4*)&Bs[0][bR][bC]     = vb;
    }
    __syncthreads();
    int cur = 0;
    for (int t = 0; t < 15; ++t) {
        int k0 = (t + 1) * 32;
        uint4 va0 = *(const uint4*)(Ap + k0);
        uint4 va1 = *(const uint4*)(Ap + k0 + 8);
        uint4 vb  = *(const uint4*)(Bp + k0);
        bf16x8 a[4], bq[2];
#pragma unroll
        for (int i = 0; i < 4; ++i) a[i] = *(const bf16x8*)&As[cur][wr * 64 + i * 16 + lr][lg * 8];
#pragma unroll
        for (int j = 0; j < 2; ++j) bq[j] = *(const bf16x8*)&Bs[cur][wc * 32 + j * 16 + lr][lg * 8];
#pragma unroll
        for (int i = 0; i < 4; ++i)
#pragma unroll
            for (int j = 0; j < 2; ++j)
                acc[i][j] = __builtin_amdgcn_mfma_f32_16x16x32_bf16(a[i], bq[j], acc[i][j], 0, 0, 0);
        *(uint4*)&As[cur ^ 1][aR][aC]     = va0;
        *(uint4*)&As[cur ^ 1][aR][aC + 8] = va1;
        *(uint4*)&Bs[cur ^ 1][bR][bC]     = vb;
        __syncthreads();
        cur ^= 1;
    }
    {
        bf16x8 a[4], bq[2];
#pragma unroll
        for (int i = 0; i < 4; ++i) a[i] = *(const bf16x8*)&As[cur][wr * 64 + i * 16 + lr][lg * 8];
#pragma unroll
        for (int j = 0; j < 2; ++j) bq[j] = *(const bf16x8*)&Bs[cur][wc * 32 + j * 16 + lr][lg * 8];
#pragma unroll
        for (int i = 0; i < 4; ++i)
#pragma unroll
            for (int j = 0; j < 2; ++j)
                acc[i][j] = __builtin_amdgcn_mfma_f32_16x16x32_bf16(a[i], bq[j], acc[i][j], 0, 0, 0);
    }
#pragma unroll
    for (int i = 0; i < 4; ++i) {
#pragma unroll
        for (int j = 0; j < 2; ++j) {
            int n = n0 + wc * 32 + j * 16 + lr;
#pragma unroll
            for (int r = 0; r < 4; ++r) {
                int m = m0 + wr * 64 + i * 16 + lg * 4 + r;
                int rr = ((m & 63) << 5) | ((m >> 6) << 2) | s;
                out[((size_t)bb * L + rr) * D + n] = acc[i][j][r];
            }
        }
    }
}

extern "C" void kernel_launch(void* const* d_in, const int* in_sizes, int n_in,
                              void* d_out, int out_size, void* d_ws, size_t ws_size,
                              hipStream_t stream) {
    const float* queries = (const float*)d_in[0];
    const float* keys    = (const float*)d_in[1];
    const float* values  = (const float*)d_in[2];
    const float* wq      = (const float*)d_in[3];
    const float* wk      = (const float*)d_in[4];
    const float* wv      = (const float*)d_in[5];
    const float* wo      = (const float*)d_in[6];
    float* out = (float*)d_out;
    char* ws = (char*)d_ws;

    unsigned short* vmixb = (unsigned short*)(ws + VMIXB_OFF);
    unsigned short* Tt    = (unsigned short*)(ws + TT_OFF);
    unsigned short* wvT   = (unsigned short*)(ws + WVT_OFF);
    unsigned short* woT   = (unsigned short*)(ws + WOT_OFF);
    float* qpart = (float*)(ws + QPART_OFF);
    float* tpart = (float*)(ws + TPART_OFF);
    float* u     = (float*)(ws + U_OFF);
    float* sc    = (float*)(ws + SC_OFF);

    k_prep1<<<384, 256, 0, stream>>>(queries, wv, wo, qpart, wvT, woT);
    k_tpart<<<dim3(B, 8), 256, 0, stream>>>(wq, qpart, tpart);
    k_uvec<<<dim3(B, 32), 256, 0, stream>>>(wk, tpart, u);
    k_scores<<<dim3(B, 128), 256, 0, stream>>>(keys, u, sc);
    k_vmixb<<<512, 256, 0, stream>>>(values, sc, (uint4*)vmixb);
    k_gemm1<<<dim3(64, 8), 256, 0, stream>>>(vmixb, wvT, Tt);
    k_gemm2<<<dim3(4, 8, 16), 256, 0, stream>>>(Tt, woT, out);
}